// Round 2
// baseline (554.611 us; speedup 1.0000x reference)
//
#include <hip/hip_runtime.h>

// One thread per row. State + full trajectory in registers (traj packed as
// bf16 pairs, 2 floats/VGPR); single contiguous write burst per row at the
// end so every output cache line is written back exactly once.

constexpr int kB     = 262144;
constexpr int kSteps = 15;

__device__ __forceinline__ float relu_(float v) { return fmaxf(v, 0.0f); }
__device__ __forceinline__ float sigmoid_(float v) {
    return __builtin_amdgcn_rcpf(1.0f + __expf(-v));
}
// round-to-nearest-even f32->bf16, packed pair (a=lo, b=hi)
__device__ __forceinline__ unsigned bfp(float a, float b) {
    unsigned ua = __float_as_uint(a); ua = (ua + 0x7FFFu + ((ua >> 16) & 1u)) >> 16;
    unsigned ub = __float_as_uint(b); ub = (ub + 0x7FFFu + ((ub >> 16) & 1u)) >> 16;
    return ua | (ub << 16);
}
__device__ __forceinline__ float2 unp(unsigned v) {
    return make_float2(__uint_as_float(v << 16), __uint_as_float(v & 0xFFFF0000u));
}

__global__ __launch_bounds__(256, 4) void Program_4578435138231_kernel(
    const float* __restrict__ x,
    const float* __restrict__ c1w, const float* __restrict__ c1b,
    const float* __restrict__ c2w, const float* __restrict__ c2b,
    const float* __restrict__ l1w, const float* __restrict__ l1b,
    const float* __restrict__ l2w, const float* __restrict__ l2b,
    float* __restrict__ out)
{
    const int i = blockIdx.x * 256 + threadIdx.x;
    if (i >= kB) return;

    const float2* xr = reinterpret_cast<const float2*>(x + (size_t)i * 18);
    float s[18];
    #pragma unroll
    for (int j = 0; j < 9; ++j) {
        float2 v = xr[j];
        s[2 * j]     = v.x;
        s[2 * j + 1] = v.y;
    }

    const float cw10 = c1w[0], cw11 = c1w[1], cb1 = c1b[0];
    const float cw20 = c2w[0], cw21 = c2w[1], cb2 = c2b[0];

    {
        float dA = s[1] - s[3], dB = s[2] - s[4];
        s[10] = dA * dA + dB * dB;
    }

    // 16 records x 10 floats, packed 2-per-VGPR as bf16 -> 80 regs
    unsigned traj[80];
    traj[0] = bfp(s[10], s[1]);
    traj[1] = bfp(s[2],  s[3]);
    traj[2] = bfp(s[4],  s[5]);
    traj[3] = bfp(s[6],  s[7]);
    traj[4] = bfp(s[8],  s[17]);

    #pragma unroll
    for (int t = 0; t < kSteps; ++t) {
        float f0 = s[1], f1 = s[2], f2 = s[3], f3 = s[4], f4 = s[9], f5 = s[17];
        float h10 = relu_(cw10 * f0 + cw11 * f1 + cb1);
        float h11 = relu_(cw10 * f1 + cw11 * f2 + cb1);
        float h12 = relu_(cw10 * f2 + cw11 * f3 + cb1);
        float h13 = relu_(cw10 * f3 + cw11 * f4 + cb1);
        float h14 = relu_(cw10 * f4 + cw11 * f5 + cb1);
        float g0 = relu_(cw20 * h10 + cw21 * h11 + cb2);
        float g1 = relu_(cw20 * h11 + cw21 * h12 + cb2);
        float g2 = relu_(cw20 * h12 + cw21 * h13 + cb2);
        float g3 = relu_(cw20 * h13 + cw21 * h14 + cb2);

        float p0 = l2b[0], p1 = l2b[1], p2 = l2b[2], p3 = l2b[3], p4 = l2b[4];
        #pragma unroll
        for (int k = 0; k < 32; ++k) {
            float h = g0 * l1w[k] + g1 * l1w[32 + k] + g2 * l1w[64 + k]
                    + g3 * l1w[96 + k] + l1b[k];
            h = relu_(h);
            p0 += h * l2w[5 * k + 0];
            p1 += h * l2w[5 * k + 1];
            p2 += h * l2w[5 * k + 2];
            p3 += h * l2w[5 * k + 3];
            p4 += h * l2w[5 * k + 4];
        }
        p0 = sigmoid_(p0); p1 = sigmoid_(p1); p2 = sigmoid_(p2);
        p3 = sigmoid_(p3); p4 = sigmoid_(p4);

        s[5] = p0; s[6] = p1; s[7] = p2; s[8] = p3; s[17] = p4;
        float a = p1 - p0, b = p2 - p0, c = p3 - p0;
        float d = p2 - p1, e = p3 - p1, f = p3 - p2;
        s[11] = a; s[12] = b; s[13] = c; s[14] = d; s[15] = e; s[16] = f;

        float dx_c = (c <= 0.f) ? 0.f  : 5.f,  st_c = (c <= 0.f) ? 0.f : 3.f;
        float dx_f = (f <= 0.f) ? 0.f  : 5.f,  st_f = (f <= 0.f) ? 2.f : 3.f;
        float dx_e = (e <= 0.f) ? -5.f : 5.f,  st_e = (e <= 0.f) ? 1.f : 3.f;
        float dx_b = (b <= 0.f) ? dx_c : dx_f, st_b = (b <= 0.f) ? st_c : st_f;
        float dx_d = (d <= 0.f) ? dx_e : dx_f, st_d = (d <= 0.f) ? st_e : st_f;
        float dx   = (a <= 0.f) ? dx_b : dx_d, st   = (a <= 0.f) ? st_b : st_d;

        s[1] += dx; s[9] = st;
        s[2] += 5.f; s[3] += 5.f; s[0] += 1.f;
        float dA = s[1] - s[3], dB = s[2] - s[4];
        s[10] = dA * dA + dB * dB;

        const int r = (t + 1) * 5;
        traj[r + 0] = bfp(s[10], s[1]);
        traj[r + 1] = bfp(s[2],  s[3]);
        traj[r + 2] = bfp(s[4],  s[5]);
        traj[r + 3] = bfp(s[6],  s[7]);
        traj[r + 4] = bfp(s[8],  s[17]);
    }

    // ---- single contiguous write burst: 89 float2 = 712 B per row ----
    float2* o2 = reinterpret_cast<float2*>(out + (size_t)i * 178);
    #pragma unroll
    for (int j = 0; j < 9; ++j) o2[j] = make_float2(s[2 * j], s[2 * j + 1]);
    #pragma unroll
    for (int r = 0; r < 80; ++r) o2[9 + r] = unp(traj[r]);
}

extern "C" void kernel_launch(void* const* d_in, const int* in_sizes, int n_in,
                              void* d_out, int out_size, void* d_ws, size_t ws_size,
                              hipStream_t stream) {
    const float* x   = (const float*)d_in[0];
    const float* c1w = (const float*)d_in[1];
    const float* c1b = (const float*)d_in[2];
    const float* c2w = (const float*)d_in[3];
    const float* c2b = (const float*)d_in[4];
    const float* l1w = (const float*)d_in[5];
    const float* l1b = (const float*)d_in[6];
    const float* l2w = (const float*)d_in[7];
    const float* l2b = (const float*)d_in[8];
    float* out = (float*)d_out;

    Program_4578435138231_kernel<<<kB / 256, 256, 0, stream>>>(
        x, c1w, c1b, c2w, c2b, l1w, l1b, l2w, l2b, out);
}

// Round 3
// 354.661 us; speedup vs baseline: 1.5638x; 1.5638x over previous
//
#include <hip/hip_runtime.h>

// One thread per row; compact trajectory in registers (4 dwords/record:
// f32 s1 + bf16x2 sigmoid pairs; s2/s3/s4/s10 reconstructed at flush).
// Input staged in via coalesced uint2 -> LDS; output expanded to bf16 pairs
// and flushed in 4 LDS-staged rounds with lane-consecutive float2 stores so
// every HBM line is touched coalesced and written back exactly once.

constexpr int kB      = 262144;
constexpr int kStride = 23;   // LDS row stride in dwords (odd -> bank-friendly)

__device__ __forceinline__ float relu_(float v) { return fmaxf(v, 0.0f); }
__device__ __forceinline__ float sigmoid_(float v) {
    return __builtin_amdgcn_rcpf(1.0f + __expf(-v));
}
__device__ __forceinline__ unsigned bf1(float a) {  // f32 -> bf16 bits (RNE)
    unsigned u = __float_as_uint(a);
    return (u + 0x7FFFu + ((u >> 16) & 1u)) >> 16;
}
__device__ __forceinline__ unsigned bfp(float a, float b) {
    return bf1(a) | (bf1(b) << 16);
}

struct Wts {
    float cw10, cw11, cb1, cw20, cw21, cb2;
    const float *l1w, *l1b, *l2w, *l2b;
};

__device__ __forceinline__ void stepf(float* s, unsigned* rec, const Wts& w) {
    float f0 = s[1], f1 = s[2], f2 = s[3], f3 = s[4], f4 = s[9], f5 = s[17];
    float h10 = relu_(w.cw10 * f0 + w.cw11 * f1 + w.cb1);
    float h11 = relu_(w.cw10 * f1 + w.cw11 * f2 + w.cb1);
    float h12 = relu_(w.cw10 * f2 + w.cw11 * f3 + w.cb1);
    float h13 = relu_(w.cw10 * f3 + w.cw11 * f4 + w.cb1);
    float h14 = relu_(w.cw10 * f4 + w.cw11 * f5 + w.cb1);
    float g0 = relu_(w.cw20 * h10 + w.cw21 * h11 + w.cb2);
    float g1 = relu_(w.cw20 * h11 + w.cw21 * h12 + w.cb2);
    float g2 = relu_(w.cw20 * h12 + w.cw21 * h13 + w.cb2);
    float g3 = relu_(w.cw20 * h13 + w.cw21 * h14 + w.cb2);

    float p0 = w.l2b[0], p1 = w.l2b[1], p2 = w.l2b[2], p3 = w.l2b[3], p4 = w.l2b[4];
    #pragma unroll
    for (int k = 0; k < 32; ++k) {
        float h = g0 * w.l1w[k] + g1 * w.l1w[32 + k] + g2 * w.l1w[64 + k]
                + g3 * w.l1w[96 + k] + w.l1b[k];
        h = relu_(h);
        p0 += h * w.l2w[5 * k + 0];
        p1 += h * w.l2w[5 * k + 1];
        p2 += h * w.l2w[5 * k + 2];
        p3 += h * w.l2w[5 * k + 3];
        p4 += h * w.l2w[5 * k + 4];
    }
    p0 = sigmoid_(p0); p1 = sigmoid_(p1); p2 = sigmoid_(p2);
    p3 = sigmoid_(p3); p4 = sigmoid_(p4);

    s[5] = p0; s[6] = p1; s[7] = p2; s[8] = p3; s[17] = p4;
    float a = p1 - p0, b = p2 - p0, c = p3 - p0;
    float d = p2 - p1, e = p3 - p1, f = p3 - p2;
    s[11] = a; s[12] = b; s[13] = c; s[14] = d; s[15] = e; s[16] = f;

    float dx_c = (c <= 0.f) ? 0.f  : 5.f,  st_c = (c <= 0.f) ? 0.f : 3.f;
    float dx_f = (f <= 0.f) ? 0.f  : 5.f,  st_f = (f <= 0.f) ? 2.f : 3.f;
    float dx_e = (e <= 0.f) ? -5.f : 5.f,  st_e = (e <= 0.f) ? 1.f : 3.f;
    float dx_b = (b <= 0.f) ? dx_c : dx_f, st_b = (b <= 0.f) ? st_c : st_f;
    float dx_d = (d <= 0.f) ? dx_e : dx_f, st_d = (d <= 0.f) ? st_e : st_f;
    float dx   = (a <= 0.f) ? dx_b : dx_d, st   = (a <= 0.f) ? st_b : st_d;

    s[1] += dx; s[9] = st;
    s[2] += 5.f; s[3] += 5.f; s[0] += 1.f;
    float dA = s[1] - s[3], dB = s[2] - s[4];
    s[10] = dA * dA + dB * dB;

    rec[0] = __float_as_uint(s[1]);
    rec[1] = bfp(p0, p1);
    rec[2] = bfp(p2, p3);
    rec[3] = bfp(p4, 0.f);
}

template<int Wd, int SB>
__device__ __forceinline__ void flush_round(unsigned* lds, float2* outBlk, int tid,
                                            const float* s, const unsigned* rec,
                                            float s2_0, float s3_0) {
    #pragma unroll
    for (int j = 0; j < Wd; ++j) {
        const int rd = SB + j;
        unsigned v;
        if (rd < 9) {
            v = bfp(s[2 * rd], s[2 * rd + 1]);               // final state pairs
        } else {
            const int d = rd - 9, r = d / 5, q = d - 5 * r;  // all constants
            const unsigned w0 = rec[4 * r + 0], w1 = rec[4 * r + 1];
            const unsigned w2 = rec[4 * r + 2], w3 = rec[4 * r + 3];
            if (q == 0) {
                float s1 = __uint_as_float(w0);
                float s2 = s2_0 + 5.f * r, s3 = s3_0 + 5.f * r;
                float dA = s1 - s3, dB = s2 - s[4];
                v = bfp(dA * dA + dB * dB, s1);              // (s10, s1)
            } else if (q == 1) {
                v = bfp(s2_0 + 5.f * r, s3_0 + 5.f * r);     // (s2, s3)
            } else if (q == 2) {
                v = bf1(s[4]) | (w1 << 16);                  // (s4, p0)
            } else if (q == 3) {
                v = (w1 >> 16) | (w2 << 16);                 // (p1, p2)
            } else {
                v = (w2 >> 16) | (w3 << 16);                 // (p3, p4)
            }
        }
        lds[tid * kStride + j] = v;
    }
    __syncthreads();
    #pragma unroll
    for (int k = 0; k < Wd; ++k) {
        int g = tid + 256 * k;
        int r = g / Wd;                 // constant divisor -> magic mul
        int c = g - r * Wd;
        unsigned v = lds[r * kStride + c];
        outBlk[(size_t)r * 89 + (SB + c)] =
            make_float2(__uint_as_float(v << 16), __uint_as_float(v & 0xFFFF0000u));
    }
    __syncthreads();
}

__global__ __launch_bounds__(256, 2) void Program_4578435138231_kernel(
    const float* __restrict__ x,
    const float* __restrict__ c1w, const float* __restrict__ c1b,
    const float* __restrict__ c2w, const float* __restrict__ c2b,
    const float* __restrict__ l1w, const float* __restrict__ l1b,
    const float* __restrict__ l2w, const float* __restrict__ l2b,
    float* __restrict__ out)
{
    __shared__ unsigned lds[256 * kStride];
    const int tid  = threadIdx.x;
    const int row0 = blockIdx.x * 256;

    // ---- coalesced input stage: 256 rows x 18 f32 = 2304 uint2 ----
    {
        const uint2* src = reinterpret_cast<const uint2*>(x + (size_t)row0 * 18);
        #pragma unroll
        for (int k = 0; k < 9; ++k) {
            int g = tid + 256 * k;      // < 2304
            int r = g / 9;              // 9 uint2 per row
            int c = g - r * 9;
            uint2 v = src[g];
            lds[r * 19 + 2 * c]     = v.x;   // staged at stride 19 (odd)
            lds[r * 19 + 2 * c + 1] = v.y;
        }
    }
    __syncthreads();
    float s[18];
    #pragma unroll
    for (int j = 0; j < 18; ++j) s[j] = __uint_as_float(lds[tid * 19 + j]);
    __syncthreads();   // all reads done before flush rounds reuse the LDS

    const Wts w{c1w[0], c1w[1], c1b[0], c2w[0], c2w[1], c2b[0], l1w, l1b, l2w, l2b};

    float dA = s[1] - s[3], dB = s[2] - s[4];
    s[10] = dA * dA + dB * dB;
    const float s2_0 = s[2], s3_0 = s[3];

    unsigned rec[64];
    rec[0] = __float_as_uint(s[1]);            // traj0 (t=0)
    rec[1] = bfp(s[5], s[6]);
    rec[2] = bfp(s[7], s[8]);
    rec[3] = bfp(s[17], 0.f);

    stepf(s, rec + 4,  w);  stepf(s, rec + 8,  w);  stepf(s, rec + 12, w);
    stepf(s, rec + 16, w);  stepf(s, rec + 20, w);  stepf(s, rec + 24, w);
    stepf(s, rec + 28, w);  stepf(s, rec + 32, w);  stepf(s, rec + 36, w);
    stepf(s, rec + 40, w);  stepf(s, rec + 44, w);  stepf(s, rec + 48, w);
    stepf(s, rec + 52, w);  stepf(s, rec + 56, w);  stepf(s, rec + 60, w);

    float2* outBlk = reinterpret_cast<float2*>(out + (size_t)row0 * 178);
    flush_round<23,  0>(lds, outBlk, tid, s, rec, s2_0, s3_0);
    flush_round<22, 23>(lds, outBlk, tid, s, rec, s2_0, s3_0);
    flush_round<22, 45>(lds, outBlk, tid, s, rec, s2_0, s3_0);
    flush_round<22, 67>(lds, outBlk, tid, s, rec, s2_0, s3_0);
}

extern "C" void kernel_launch(void* const* d_in, const int* in_sizes, int n_in,
                              void* d_out, int out_size, void* d_ws, size_t ws_size,
                              hipStream_t stream) {
    const float* x   = (const float*)d_in[0];
    const float* c1w = (const float*)d_in[1];
    const float* c1b = (const float*)d_in[2];
    const float* c2w = (const float*)d_in[3];
    const float* c2b = (const float*)d_in[4];
    const float* l1w = (const float*)d_in[5];
    const float* l1b = (const float*)d_in[6];
    const float* l2w = (const float*)d_in[7];
    const float* l2b = (const float*)d_in[8];
    float* out = (float*)d_out;

    Program_4578435138231_kernel<<<kB / 256, 256, 0, stream>>>(
        x, c1w, c1b, c2w, c2b, l1w, l1b, l2w, l2b, out);
}

// Round 4
// 320.774 us; speedup vs baseline: 1.7290x; 1.1056x over previous
//
#include <hip/hip_runtime.h>

// Two consecutive rows per thread; rolled t-loop (small I$); fused k-loop so
// each scalar weight load feeds 2 rows' FMAs (2x arithmetic intensity per
// lgkm wait, 2 independent dep chains). Per-step f32 float2 stores (R1's
// proven write path). Input as 9x float4 per thread (row pair = 144 B).

constexpr int kB     = 262144;
constexpr int kSteps = 15;

__device__ __forceinline__ float relu_(float v) { return fmaxf(v, 0.0f); }
__device__ __forceinline__ float sigmoid_(float v) {
    return __builtin_amdgcn_rcpf(1.0f + __expf(-v));
}

__global__ __launch_bounds__(256) void Program_4578435138231_kernel(
    const float* __restrict__ x,
    const float* __restrict__ c1w, const float* __restrict__ c1b,
    const float* __restrict__ c2w, const float* __restrict__ c2b,
    const float* __restrict__ l1w, const float* __restrict__ l1b,
    const float* __restrict__ l2w, const float* __restrict__ l2b,
    float* __restrict__ out)
{
    const int i = blockIdx.x * 256 + threadIdx.x;   // 0 .. 131071
    if (i >= kB / 2) return;

    // ---- load 2 rows (36 f32, 16B-aligned) as 9x float4 ----
    float tmp[36];
    const float4* xr = reinterpret_cast<const float4*>(x + (size_t)i * 36);
    #pragma unroll
    for (int j = 0; j < 9; ++j) {
        float4 v = xr[j];
        tmp[4 * j + 0] = v.x; tmp[4 * j + 1] = v.y;
        tmp[4 * j + 2] = v.z; tmp[4 * j + 3] = v.w;
    }
    float sA[18], sB[18];
    #pragma unroll
    for (int j = 0; j < 18; ++j) { sA[j] = tmp[j]; sB[j] = tmp[18 + j]; }

    const float cw10 = c1w[0], cw11 = c1w[1], cb1 = c1b[0];
    const float cw20 = c2w[0], cw21 = c2w[1], cb2 = c2b[0];

    {
        float dA = sA[1] - sA[3], dB = sA[2] - sA[4];
        sA[10] = dA * dA + dB * dB;
        float dC = sB[1] - sB[3], dD = sB[2] - sB[4];
        sB[10] = dC * dC + dD * dD;
    }

    float* orowA = out + (size_t)(2 * i) * 178;
    float* orowB = orowA + 178;

    // traj0 records (offset 18 floats -> 8B aligned)
    {
        float2* trA = reinterpret_cast<float2*>(orowA + 18);
        trA[0] = make_float2(sA[10], sA[1]); trA[1] = make_float2(sA[2], sA[3]);
        trA[2] = make_float2(sA[4],  sA[5]); trA[3] = make_float2(sA[6], sA[7]);
        trA[4] = make_float2(sA[8],  sA[17]);
        float2* trB = reinterpret_cast<float2*>(orowB + 18);
        trB[0] = make_float2(sB[10], sB[1]); trB[1] = make_float2(sB[2], sB[3]);
        trB[2] = make_float2(sB[4],  sB[5]); trB[3] = make_float2(sB[6], sB[7]);
        trB[4] = make_float2(sB[8],  sB[17]);
    }

    #pragma unroll 1
    for (int t = 0; t < kSteps; ++t) {
        // ---- classifier front (both rows) ----
        float a10 = relu_(cw10 * sA[1] + cw11 * sA[2] + cb1);
        float a11 = relu_(cw10 * sA[2] + cw11 * sA[3] + cb1);
        float a12 = relu_(cw10 * sA[3] + cw11 * sA[4] + cb1);
        float a13 = relu_(cw10 * sA[4] + cw11 * sA[9] + cb1);
        float a14 = relu_(cw10 * sA[9] + cw11 * sA[17] + cb1);
        float b10 = relu_(cw10 * sB[1] + cw11 * sB[2] + cb1);
        float b11 = relu_(cw10 * sB[2] + cw11 * sB[3] + cb1);
        float b12 = relu_(cw10 * sB[3] + cw11 * sB[4] + cb1);
        float b13 = relu_(cw10 * sB[4] + cw11 * sB[9] + cb1);
        float b14 = relu_(cw10 * sB[9] + cw11 * sB[17] + cb1);

        float gA0 = relu_(cw20 * a10 + cw21 * a11 + cb2);
        float gA1 = relu_(cw20 * a11 + cw21 * a12 + cb2);
        float gA2 = relu_(cw20 * a12 + cw21 * a13 + cb2);
        float gA3 = relu_(cw20 * a13 + cw21 * a14 + cb2);
        float gB0 = relu_(cw20 * b10 + cw21 * b11 + cb2);
        float gB1 = relu_(cw20 * b11 + cw21 * b12 + cb2);
        float gB2 = relu_(cw20 * b12 + cw21 * b13 + cb2);
        float gB3 = relu_(cw20 * b13 + cw21 * b14 + cb2);

        // ---- fused k-loop: 10 scalar weights -> 20 FMAs ----
        float pA0 = l2b[0], pA1 = l2b[1], pA2 = l2b[2], pA3 = l2b[3], pA4 = l2b[4];
        float pB0 = pA0, pB1 = pA1, pB2 = pA2, pB3 = pA3, pB4 = pA4;
        #pragma unroll
        for (int k = 0; k < 32; ++k) {
            float w0 = l1w[k], w1 = l1w[32 + k], w2 = l1w[64 + k], w3 = l1w[96 + k];
            float bb = l1b[k];
            float v0 = l2w[5 * k + 0], v1 = l2w[5 * k + 1], v2 = l2w[5 * k + 2];
            float v3 = l2w[5 * k + 3], v4 = l2w[5 * k + 4];
            float hA = relu_(gA0 * w0 + gA1 * w1 + gA2 * w2 + gA3 * w3 + bb);
            float hB = relu_(gB0 * w0 + gB1 * w1 + gB2 * w2 + gB3 * w3 + bb);
            pA0 += hA * v0; pB0 += hB * v0;
            pA1 += hA * v1; pB1 += hB * v1;
            pA2 += hA * v2; pB2 += hB * v2;
            pA3 += hA * v3; pB3 += hB * v3;
            pA4 += hA * v4; pB4 += hB * v4;
        }
        pA0 = sigmoid_(pA0); pA1 = sigmoid_(pA1); pA2 = sigmoid_(pA2);
        pA3 = sigmoid_(pA3); pA4 = sigmoid_(pA4);
        pB0 = sigmoid_(pB0); pB1 = sigmoid_(pB1); pB2 = sigmoid_(pB2);
        pB3 = sigmoid_(pB3); pB4 = sigmoid_(pB4);

        // ---- decisions + state update, row A ----
        {
            sA[5] = pA0; sA[6] = pA1; sA[7] = pA2; sA[8] = pA3; sA[17] = pA4;
            float a = pA1 - pA0, b = pA2 - pA0, c = pA3 - pA0;
            float d = pA2 - pA1, e = pA3 - pA1, f = pA3 - pA2;
            sA[11] = a; sA[12] = b; sA[13] = c; sA[14] = d; sA[15] = e; sA[16] = f;
            float dx_c = (c <= 0.f) ? 0.f  : 5.f,  st_c = (c <= 0.f) ? 0.f : 3.f;
            float dx_f = (f <= 0.f) ? 0.f  : 5.f,  st_f = (f <= 0.f) ? 2.f : 3.f;
            float dx_e = (e <= 0.f) ? -5.f : 5.f,  st_e = (e <= 0.f) ? 1.f : 3.f;
            float dx_b = (b <= 0.f) ? dx_c : dx_f, st_b = (b <= 0.f) ? st_c : st_f;
            float dx_d = (d <= 0.f) ? dx_e : dx_f, st_d = (d <= 0.f) ? st_e : st_f;
            float dx   = (a <= 0.f) ? dx_b : dx_d, st   = (a <= 0.f) ? st_b : st_d;
            sA[1] += dx; sA[9] = st;
            sA[2] += 5.f; sA[3] += 5.f; sA[0] += 1.f;
            float dA = sA[1] - sA[3], dB = sA[2] - sA[4];
            sA[10] = dA * dA + dB * dB;
        }
        // ---- decisions + state update, row B ----
        {
            sB[5] = pB0; sB[6] = pB1; sB[7] = pB2; sB[8] = pB3; sB[17] = pB4;
            float a = pB1 - pB0, b = pB2 - pB0, c = pB3 - pB0;
            float d = pB2 - pB1, e = pB3 - pB1, f = pB3 - pB2;
            sB[11] = a; sB[12] = b; sB[13] = c; sB[14] = d; sB[15] = e; sB[16] = f;
            float dx_c = (c <= 0.f) ? 0.f  : 5.f,  st_c = (c <= 0.f) ? 0.f : 3.f;
            float dx_f = (f <= 0.f) ? 0.f  : 5.f,  st_f = (f <= 0.f) ? 2.f : 3.f;
            float dx_e = (e <= 0.f) ? -5.f : 5.f,  st_e = (e <= 0.f) ? 1.f : 3.f;
            float dx_b = (b <= 0.f) ? dx_c : dx_f, st_b = (b <= 0.f) ? st_c : st_f;
            float dx_d = (d <= 0.f) ? dx_e : dx_f, st_d = (d <= 0.f) ? st_e : st_f;
            float dx   = (a <= 0.f) ? dx_b : dx_d, st   = (a <= 0.f) ? st_b : st_d;
            sB[1] += dx; sB[9] = st;
            sB[2] += 5.f; sB[3] += 5.f; sB[0] += 1.f;
            float dA = sB[1] - sB[3], dB = sB[2] - sB[4];
            sB[10] = dA * dA + dB * dB;
        }

        // ---- trajectory records ----
        float2* trA = reinterpret_cast<float2*>(orowA + 18 + 10 * (t + 1));
        trA[0] = make_float2(sA[10], sA[1]); trA[1] = make_float2(sA[2], sA[3]);
        trA[2] = make_float2(sA[4],  sA[5]); trA[3] = make_float2(sA[6], sA[7]);
        trA[4] = make_float2(sA[8],  sA[17]);
        float2* trB = reinterpret_cast<float2*>(orowB + 18 + 10 * (t + 1));
        trB[0] = make_float2(sB[10], sB[1]); trB[1] = make_float2(sB[2], sB[3]);
        trB[2] = make_float2(sB[4],  sB[5]); trB[3] = make_float2(sB[6], sB[7]);
        trB[4] = make_float2(sB[8],  sB[17]);
    }

    // ---- final states ----
    float2* oA = reinterpret_cast<float2*>(orowA);
    float2* oB = reinterpret_cast<float2*>(orowB);
    #pragma unroll
    for (int j = 0; j < 9; ++j) {
        oA[j] = make_float2(sA[2 * j], sA[2 * j + 1]);
        oB[j] = make_float2(sB[2 * j], sB[2 * j + 1]);
    }
}

extern "C" void kernel_launch(void* const* d_in, const int* in_sizes, int n_in,
                              void* d_out, int out_size, void* d_ws, size_t ws_size,
                              hipStream_t stream) {
    const float* x   = (const float*)d_in[0];
    const float* c1w = (const float*)d_in[1];
    const float* c1b = (const float*)d_in[2];
    const float* c2w = (const float*)d_in[3];
    const float* c2b = (const float*)d_in[4];
    const float* l1w = (const float*)d_in[5];
    const float* l1b = (const float*)d_in[6];
    const float* l2w = (const float*)d_in[7];
    const float* l2b = (const float*)d_in[8];
    float* out = (float*)d_out;

    Program_4578435138231_kernel<<<(kB / 2) / 256, 256, 0, stream>>>(
        x, c1w, c1b, c2w, c2b, l1w, l1b, l2w, l2b, out);
}

// Round 6
// 308.805 us; speedup vs baseline: 1.7960x; 1.0388x over previous
//
#include <hip/hip_runtime.h>

// One thread per row, wave-sized (64-thread) blocks, NO early-exit so the
// whole body is uniform control flow -> weight loads scalarize to s_load
// (K$-resident) instead of per-lane global_load re-fetched every k-iter.
// Trajectory records are packed to bf16 pairs per step directly into LDS in
// final output layout, then flushed with coalesced float2 stores in two
// 40-dword chunks + one 9-dword state chunk. LDS 64x41 dwords = 10.5 KB
// -> 15 blocks/CU. All barriers are intra-wave (free).

constexpr int kB = 262144;

__device__ __forceinline__ float relu_(float v) { return fmaxf(v, 0.0f); }
__device__ __forceinline__ float sigmoid_(float v) {
    return __builtin_amdgcn_rcpf(1.0f + __expf(-v));
}
// f32 -> bf16 bits, round-to-nearest-even (hand-rolled; trivially copyable)
__device__ __forceinline__ unsigned bf1(float a) {
    unsigned u = __float_as_uint(a);
    return (u + 0x7FFFu + ((u >> 16) & 1u)) >> 16;
}
__device__ __forceinline__ unsigned pkbf(float lo, float hi) {
    return bf1(lo) | (bf1(hi) << 16);
}

__global__ __launch_bounds__(64) void Program_4578435138231_kernel(
    const float* __restrict__ x,
    const float* __restrict__ c1w, const float* __restrict__ c1b,
    const float* __restrict__ c2w, const float* __restrict__ c2b,
    const float* __restrict__ l1w, const float* __restrict__ l1b,
    const float* __restrict__ l2w, const float* __restrict__ l2b,
    float* __restrict__ out)
{
    __shared__ unsigned lds[64 * 41];
    const int tid  = threadIdx.x;
    const int row0 = blockIdx.x * 64;
    const int row  = row0 + tid;          // grid exactly covers kB: no guard

    // ---- load row: 9x float2 (8B-aligned) ----
    const float2* xr = reinterpret_cast<const float2*>(x + (size_t)row * 18);
    float s[18];
    #pragma unroll
    for (int j = 0; j < 9; ++j) {
        float2 v = xr[j];
        s[2 * j] = v.x; s[2 * j + 1] = v.y;
    }

    const float cw10 = c1w[0], cw11 = c1w[1], cb1 = c1b[0];
    const float cw20 = c2w[0], cw21 = c2w[1], cb2 = c2b[0];

    {
        float dA = s[1] - s[3], dB = s[2] - s[4];
        s[10] = dA * dA + dB * dB;
    }

    auto write_rec = [&](int col) {
        const int base = tid * 41 + col;
        lds[base + 0] = pkbf(s[10], s[1]);
        lds[base + 1] = pkbf(s[2],  s[3]);
        lds[base + 2] = pkbf(s[4],  s[5]);
        lds[base + 3] = pkbf(s[6],  s[7]);
        lds[base + 4] = pkbf(s[8],  s[17]);
    };

    auto step = [&]() {
        float h10 = relu_(cw10 * s[1] + cw11 * s[2]  + cb1);
        float h11 = relu_(cw10 * s[2] + cw11 * s[3]  + cb1);
        float h12 = relu_(cw10 * s[3] + cw11 * s[4]  + cb1);
        float h13 = relu_(cw10 * s[4] + cw11 * s[9]  + cb1);
        float h14 = relu_(cw10 * s[9] + cw11 * s[17] + cb1);
        float g0 = relu_(cw20 * h10 + cw21 * h11 + cb2);
        float g1 = relu_(cw20 * h11 + cw21 * h12 + cb2);
        float g2 = relu_(cw20 * h12 + cw21 * h13 + cb2);
        float g3 = relu_(cw20 * h13 + cw21 * h14 + cb2);

        float p0 = l2b[0], p1 = l2b[1], p2 = l2b[2], p3 = l2b[3], p4 = l2b[4];
        #pragma unroll
        for (int k = 0; k < 32; ++k) {
            float h = g0 * l1w[k] + g1 * l1w[32 + k] + g2 * l1w[64 + k]
                    + g3 * l1w[96 + k] + l1b[k];
            h = relu_(h);
            p0 += h * l2w[5 * k + 0];
            p1 += h * l2w[5 * k + 1];
            p2 += h * l2w[5 * k + 2];
            p3 += h * l2w[5 * k + 3];
            p4 += h * l2w[5 * k + 4];
        }
        p0 = sigmoid_(p0); p1 = sigmoid_(p1); p2 = sigmoid_(p2);
        p3 = sigmoid_(p3); p4 = sigmoid_(p4);

        s[5] = p0; s[6] = p1; s[7] = p2; s[8] = p3; s[17] = p4;
        float a = p1 - p0, b = p2 - p0, c = p3 - p0;
        float d = p2 - p1, e = p3 - p1, f = p3 - p2;
        s[11] = a; s[12] = b; s[13] = c; s[14] = d; s[15] = e; s[16] = f;

        float dx_c = (c <= 0.f) ? 0.f  : 5.f,  st_c = (c <= 0.f) ? 0.f : 3.f;
        float dx_f = (f <= 0.f) ? 0.f  : 5.f,  st_f = (f <= 0.f) ? 2.f : 3.f;
        float dx_e = (e <= 0.f) ? -5.f : 5.f,  st_e = (e <= 0.f) ? 1.f : 3.f;
        float dx_b = (b <= 0.f) ? dx_c : dx_f, st_b = (b <= 0.f) ? st_c : st_f;
        float dx_d = (d <= 0.f) ? dx_e : dx_f, st_d = (d <= 0.f) ? st_e : st_f;
        float dx   = (a <= 0.f) ? dx_b : dx_d, st   = (a <= 0.f) ? st_b : st_d;

        s[1] += dx; s[9] = st;
        s[2] += 5.f; s[3] += 5.f; s[0] += 1.f;
        float dA = s[1] - s[3], dB = s[2] - s[4];
        s[10] = dA * dA + dB * dB;
    };

    float2* out2 = reinterpret_cast<float2*>(out);

    // flush LDS cols [0,40) -> out dwords [outD0, outD0+40) for this block's rows
    auto flush40 = [&](int outD0) {
        __syncthreads();
        #pragma unroll
        for (int k = 0; k < 40; ++k) {
            int g = tid + 64 * k;          // 0..2559 over 64 rows x 40 cols
            int r = g / 40, c = g - r * 40;
            unsigned v = lds[r * 41 + c];
            out2[(size_t)(row0 + r) * 89 + outD0 + c] =
                make_float2(__uint_as_float(v << 16),
                            __uint_as_float(v & 0xFFFF0000u));
        }
        __syncthreads();
    };

    // ---- phase 1: records r0..r7 (out dwords 9..48) ----
    write_rec(0);                                   // traj0
    #pragma unroll 1
    for (int t = 0; t < 7; ++t) { step(); write_rec(5 * (t + 1)); }
    flush40(9);

    // ---- phase 2: records r8..r15 (out dwords 49..88) ----
    #pragma unroll 1
    for (int t = 7; t < 15; ++t) { step(); write_rec(5 * (t - 7)); }
    flush40(49);

    // ---- phase 3: final state (out dwords 0..8) ----
    {
        const int base = tid * 41;
        lds[base + 0] = pkbf(s[0],  s[1]);
        lds[base + 1] = pkbf(s[2],  s[3]);
        lds[base + 2] = pkbf(s[4],  s[5]);
        lds[base + 3] = pkbf(s[6],  s[7]);
        lds[base + 4] = pkbf(s[8],  s[9]);
        lds[base + 5] = pkbf(s[10], s[11]);
        lds[base + 6] = pkbf(s[12], s[13]);
        lds[base + 7] = pkbf(s[14], s[15]);
        lds[base + 8] = pkbf(s[16], s[17]);
        __syncthreads();
        #pragma unroll
        for (int k = 0; k < 9; ++k) {
            int g = tid + 64 * k;          // 0..575 over 64 rows x 9 cols
            int r = g / 9, c = g - r * 9;
            unsigned v = lds[r * 41 + c];
            out2[(size_t)(row0 + r) * 89 + c] =
                make_float2(__uint_as_float(v << 16),
                            __uint_as_float(v & 0xFFFF0000u));
        }
    }
}

extern "C" void kernel_launch(void* const* d_in, const int* in_sizes, int n_in,
                              void* d_out, int out_size, void* d_ws, size_t ws_size,
                              hipStream_t stream) {
    const float* x   = (const float*)d_in[0];
    const float* c1w = (const float*)d_in[1];
    const float* c1b = (const float*)d_in[2];
    const float* c2w = (const float*)d_in[3];
    const float* c2b = (const float*)d_in[4];
    const float* l1w = (const float*)d_in[5];
    const float* l1b = (const float*)d_in[6];
    const float* l2w = (const float*)d_in[7];
    const float* l2b = (const float*)d_in[8];
    float* out = (float*)d_out;

    Program_4578435138231_kernel<<<kB / 64, 64, 0, stream>>>(
        x, c1w, c1b, c2w, c2b, l1w, l1b, l2w, l2b, out);
}